// Round 5
// baseline (518.793 us; speedup 1.0000x reference)
//
#include <hip/hip_runtime.h>

#define NUM_CLASSES 601
#define OUT_DIM 27
#define P_ELEMS (NUM_CLASSES * OUT_DIM)   // 16227
#define BATCH 4194304u
#define BLOCK 512u
#define GRID 1026u                        // 27*38: grid*block*4 floats % 27 == 0 (phase-aligned)

// fp16 table: 16227 * 2 B = 32454 B LDS -> 4 blocks/CU (129816 <= 163840) -> 32 waves/CU.
__global__ __launch_bounds__(BLOCK)
void trigram_probs_kernel(const int* __restrict__ idx,
                          const float* __restrict__ W,
                          float4* __restrict__ out4,
                          unsigned n4) {
    __shared__ _Float16 Ph[P_ELEMS];
    const unsigned t = threadIdx.x;

    // ---- Preamble: softmax(W) rows -> fp16 LDS table. Two-pass keeps VGPRs low.
    for (unsigned row = t; row < NUM_CLASSES; row += BLOCK) {
        const float* w = W + row * OUT_DIM;
        float s = 0.f;
        #pragma unroll
        for (int j = 0; j < OUT_DIM; ++j) s += __expf(w[j]);
        const float inv = 1.0f / s;
        #pragma unroll
        for (int j = 0; j < OUT_DIM; ++j)
            Ph[row * OUT_DIM + j] = (_Float16)(__expf(w[j]) * inv);
    }
    __syncthreads();

    // ---- Phase-aligned main loop. Stride in floats = GRID*BLOCK*4 = 2101248 = 27*77824,
    // so per-thread col pattern is loop-invariant; rows advance by exactly R_STEP.
    const unsigned T      = GRID * BLOCK;          // float4 stride
    const unsigned R_STEP = (T * 4u) / 27u;        // 77824 rows per iteration

    unsigned i = blockIdx.x * BLOCK + t;
    if (i >= n4) return;
    const unsigned e0 = i * 4u;
    unsigned r        = e0 / 27u;                  // once, at setup
    const unsigned c0 = e0 - r * 27u;
    const unsigned d  = (c0 > 23u) ? 1u : 0u;      // float4 crosses into next row?
    const unsigned r_clamp = BATCH - 1u - d;       // max legal row for this thread's pattern
    // Loop-invariant per-element (col, row-select) pattern:
    unsigned col2[4]; bool sel[4];
    #pragma unroll
    for (int k = 0; k < 4; ++k) {
        unsigned c = c0 + (unsigned)k;
        sel[k]  = (c >= 27u);
        col2[k] = (sel[k] ? (c - 27u) : c) * 2u;   // byte offset within row (fp16)
    }

    int cls0 = idx[r];
    int cls1 = idx[r + d];                          // same addr when d==0
    for (;;) {
        // Prefetch next iteration's indices. Clamp to r_clamp: never alters a live
        // continuing value (next in-bounds float4 implies r+R_STEP <= BATCH-1-d);
        // only sanitizes the discarded final prefetch. idx[rn+d] <= BATCH-1 always.
        const unsigned rn = min(r + R_STEP, r_clamp);
        const int n0 = idx[rn];
        const int n1 = idx[rn + d];

        const unsigned b0 = (unsigned)cls0 * (OUT_DIM * 2u);   // byte base of row in Ph
        const unsigned b1 = (unsigned)cls1 * (OUT_DIM * 2u);
        float v[4];
        #pragma unroll
        for (int k = 0; k < 4; ++k) {
            const unsigned a = (sel[k] ? b1 : b0) + col2[k];
            v[k] = (float)(*(const _Float16*)((const char*)Ph + a));
        }
        out4[i] = make_float4(v[0], v[1], v[2], v[3]);

        i += T;
        if (i >= n4) break;
        r = rn; cls0 = n0; cls1 = n1;
    }
}

extern "C" void kernel_launch(void* const* d_in, const int* in_sizes, int n_in,
                              void* d_out, int out_size, void* d_ws, size_t ws_size,
                              hipStream_t stream) {
    const int*   idx = (const int*)d_in[0];   // bigram_idx [4194304] int32
    const float* W   = (const float*)d_in[1]; // W [601,27] float32
    float4*      out = (float4*)d_out;        // probs [4194304,27] float32

    const unsigned n4 = (unsigned)(out_size / 4);  // 28311552
    trigram_probs_kernel<<<dim3(GRID), dim3(BLOCK), 0, stream>>>(idx, W, out, n4);
}